// Round 2
// baseline (366.355 us; speedup 1.0000x reference)
//
#include <hip/hip_runtime.h>
#include <hip/hip_bf16.h>

typedef unsigned short u16;
typedef __attribute__((ext_vector_type(8))) short short8;
typedef __attribute__((ext_vector_type(4))) float f32x4;
typedef __attribute__((ext_vector_type(4))) unsigned short u16x4;

#define DEVI static __device__ __forceinline__

DEVI u16 f2bf(float f){
  union { float f; unsigned u; } c; c.f = f;
  unsigned r = (c.u + 0x7fffu + ((c.u >> 16) & 1u)) >> 16;
  return (u16)r;
}

DEVI void async16(const void* g, void* l){
  __builtin_amdgcn_global_load_lds(
    (const __attribute__((address_space(1))) unsigned int*)g,
    (__attribute__((address_space(3))) unsigned int*)l, 16, 0, 0);
}

// ---------------- fp32 -> bf16 conversion ----------------
__global__ __launch_bounds__(256) void cvt_bf16(const float4* __restrict__ src,
                                                u16* __restrict__ dst, int n4){
  int i = blockIdx.x * 256 + threadIdx.x;
  if (i >= n4) return;
  float4 v = src[i];
  u16x4 o;
  o.x = f2bf(v.x); o.y = f2bf(v.y); o.z = f2bf(v.z); o.w = f2bf(v.w);
  *(u16x4*)(dst + (size_t)i * 4) = o;
}

// ---------------- GEMM: C[M][N] = A[M][K] * B[N][K]^T ----------------
// A,B bf16 row-major (K contiguous), C fp32. 128x128 tile, BK=32, 4 waves.
// LDS layout [kgroup g][row][8] -> conflict-free ds_read_b128, linear async dest.
__global__ __launch_bounds__(256) void gemm_bt(const u16* __restrict__ A,
                                               const u16* __restrict__ B,
                                               float* __restrict__ C,
                                               int M, int N, int K){
  __shared__ __align__(16) u16 AsF[4 * 128 * 8];
  __shared__ __align__(16) u16 BsF[4 * 128 * 8];
  const int tid  = threadIdx.x;
  const int lane = tid & 63, wid = tid >> 6;
  const int wr = wid >> 1, wc = wid & 1;       // 2x2 waves, each 64x64 out
  const int fr = lane & 15, fg = lane >> 4;
  const int mBase = blockIdx.y * 128, nBase = blockIdx.x * 128;

  f32x4 acc[4][4];
  for (int m = 0; m < 4; ++m)
    for (int n = 0; n < 4; ++n)
      for (int e = 0; e < 4; ++e) acc[m][n][e] = 0.f;

  const int ch0 = tid, ch1 = tid + 256;        // 512 chunks of 16B per tile
  const int r0 = ch0 & 127, g0 = ch0 >> 7;
  const int r1 = ch1 & 127, g1 = ch1 >> 7;
  const u16* Ab = A + (size_t)mBase * K;
  const u16* Bb = B + (size_t)nBase * K;

  const int nk = K >> 5;
  for (int kt = 0; kt < nk; ++kt){
    const int kOff = kt * 32;
    async16(Ab + (size_t)r0 * K + kOff + g0 * 8, AsF + ch0 * 8);
    async16(Ab + (size_t)r1 * K + kOff + g1 * 8, AsF + ch1 * 8);
    async16(Bb + (size_t)r0 * K + kOff + g0 * 8, BsF + ch0 * 8);
    async16(Bb + (size_t)r1 * K + kOff + g1 * 8, BsF + ch1 * 8);
    __syncthreads();
    short8 a[4], b[4];
#pragma unroll
    for (int m = 0; m < 4; ++m)
      a[m] = *(const short8*)(AsF + (fg * 128 + wr * 64 + m * 16 + fr) * 8);
#pragma unroll
    for (int n = 0; n < 4; ++n)
      b[n] = *(const short8*)(BsF + (fg * 128 + wc * 64 + n * 16 + fr) * 8);
#pragma unroll
    for (int m = 0; m < 4; ++m)
#pragma unroll
      for (int n = 0; n < 4; ++n)
        acc[m][n] = __builtin_amdgcn_mfma_f32_16x16x32_bf16(a[m], b[n], acc[m][n], 0, 0, 0);
    __syncthreads();
  }
  // epilogue: C/D layout col=lane&15, row=(lane>>4)*4+reg
  for (int m = 0; m < 4; ++m){
    const int row = mBase + wr * 64 + m * 16 + fg * 4;
    for (int n = 0; n < 4; ++n){
      const int col = nBase + wc * 64 + n * 16 + fr;
      for (int e = 0; e < 4; ++e)
        C[(size_t)(row + e) * N + col] = acc[m][n][e];
    }
  }
}

// ---------------- RoPE + gain/scale + pack to bf16 head-major ----------------
// qkv fp32 [T][3072] -> qb[32][T][64], kb[8][T][64], vb[8][T][64] (bf16)
__global__ __launch_bounds__(256) void rope_pack(const float* __restrict__ qkv,
                                                 const float* __restrict__ q_gain,
                                                 const float* __restrict__ attn_temp,
                                                 u16* __restrict__ qb,
                                                 u16* __restrict__ kb,
                                                 u16* __restrict__ vb){
  const int t = blockIdx.x;
  const float* row = qkv + (size_t)t * 3072;
  const int tid = threadIdx.x;
  const float ft = (float)t;
  // q: 32 heads x 32 rotate pairs
  for (int p = tid; p < 1024; p += 256){
    const int h = p >> 5, d = p & 31;
    const float x1 = row[h * 64 + d], x2 = row[h * 64 + d + 32];
    const float ang = ft * ((float)d * 0.03125f);
    const float s = sinf(ang), c = cosf(ang);
    const float gsc = q_gain[h] * attn_temp[h] * 0.125f;  // fold 1/sqrt(64)
    const size_t o = ((size_t)h * 2048 + t) * 64 + d;
    qb[o]      = f2bf((x1 * c - x2 * s) * gsc);
    qb[o + 32] = f2bf((x1 * s + x2 * c) * gsc);
  }
  // k: 8 heads x 32 pairs (exactly 256)
  {
    const int h = tid >> 5, d = tid & 31;
    const float x1 = row[2048 + h * 64 + d], x2 = row[2048 + h * 64 + d + 32];
    const float ang = ft * ((float)d * 0.03125f);
    const float s = sinf(ang), c = cosf(ang);
    const size_t o = ((size_t)h * 2048 + t) * 64 + d;
    kb[o]      = f2bf(x1 * c - x2 * s);
    kb[o + 32] = f2bf(x1 * s + x2 * c);
  }
  // v: 512 elems
  for (int p = tid; p < 512; p += 256){
    const int h = p >> 6, d = p & 63;
    vb[((size_t)h * 2048 + t) * 64 + d] = f2bf(row[2560 + p]);
  }
}

// ---------------- causal flash attention ----------------
// qb[32][2048][64], kb/vb[8][2048][64] -> yb[2048][2048] (t-major, col=h*64+d)
__global__ __launch_bounds__(256) void attn_fwd(const u16* __restrict__ qb,
                                                const u16* __restrict__ kb,
                                                const u16* __restrict__ vb,
                                                u16* __restrict__ yb){
  const int qt = blockIdx.x, h = blockIdx.y;
  const int hk = h >> 2;
  const int tid = threadIdx.x;
  const int lane = tid & 63, wid = tid >> 6;
  const int fr = lane & 15, fg = lane >> 4;
  const int qrow0 = qt * 64 + wid * 16;   // wave's 16 q rows

  __shared__ __align__(16) u16 KsF[2048];        // [g8][row32][8]
  __shared__ __align__(16) u16 VsF[2048];        // [g4][d64][8]  (transposed V)
  __shared__ __align__(16) u16 PsF[4 * 16 * 32]; // per-wave P tile

  short8 qf[2];
  {
    const u16* qp = qb + ((size_t)h * 2048 + qrow0 + fr) * 64 + fg * 8;
    qf[0] = *(const short8*)(qp);
    qf[1] = *(const short8*)(qp + 32);
  }

  float mrow[4], lrow[4];
  f32x4 o[4];
  for (int r = 0; r < 4; ++r){ mrow[r] = -1e30f; lrow[r] = 0.f; }
  for (int df = 0; df < 4; ++df)
    for (int e = 0; e < 4; ++e) o[df][e] = 0.f;

  const u16* kbh = kb + (size_t)hk * 2048 * 64;
  const u16* vbh = vb + (size_t)hk * 2048 * 64;

  const int ktmax = qt * 2 + 2;
  for (int kt = 0; kt < ktmax; ++kt){
    __syncthreads();
    // stage K: 256 chunks of 16B, LDS linear
    async16(kbh + (size_t)(kt * 32 + (tid & 31)) * 64 + (tid >> 5) * 8, KsF + tid * 8);
    // stage V transposed: Vs[g][d][e] = V[kt*32+g*8+e][d]
    {
      const int r = tid >> 3, d0 = (tid & 7) * 8;
      short8 v8 = *(const short8*)(vbh + (size_t)(kt * 32 + r) * 64 + d0);
      const int g = r >> 3, ee = r & 7;
#pragma unroll
      for (int j = 0; j < 8; ++j)
        VsF[(g * 64 + d0 + j) * 8 + ee] = (u16)v8[j];
    }
    __syncthreads();

    // S = Q K^T : 2 col-frags of 16 k-indices
    f32x4 s[2];
#pragma unroll
    for (int cf = 0; cf < 2; ++cf){
      for (int e = 0; e < 4; ++e) s[cf][e] = 0.f;
#pragma unroll
      for (int kc = 0; kc < 2; ++kc){
        short8 bfr = *(const short8*)(KsF + ((kc * 4 + fg) * 32 + cf * 16 + fr) * 8);
        s[cf] = __builtin_amdgcn_mfma_f32_16x16x32_bf16(qf[kc], bfr, s[cf], 0, 0, 0);
      }
    }
    // causal mask (wave-uniform skip when tile fully valid)
    if (kt * 32 + 31 > qrow0){
#pragma unroll
      for (int cf = 0; cf < 2; ++cf){
        const int kcol = kt * 32 + cf * 16 + fr;
#pragma unroll
        for (int r = 0; r < 4; ++r)
          if (kcol > qrow0 + fg * 4 + r) s[cf][r] = -1e30f;
      }
    }
    // online softmax (rows live in 16-lane groups; reduce via shfl width 16)
    float pv0[4], pv1[4];
#pragma unroll
    for (int r = 0; r < 4; ++r){
      float mt = fmaxf(s[0][r], s[1][r]);
      for (int msk = 1; msk < 16; msk <<= 1) mt = fmaxf(mt, __shfl_xor(mt, msk, 16));
      const float mn = fmaxf(mrow[r], mt);
      const float al = __expf(mrow[r] - mn);
      const float p0 = __expf(s[0][r] - mn);
      const float p1 = __expf(s[1][r] - mn);
      float rs = p0 + p1;
      for (int msk = 1; msk < 16; msk <<= 1) rs += __shfl_xor(rs, msk, 16);
      mrow[r] = mn;
      lrow[r] = lrow[r] * al + rs;
#pragma unroll
      for (int df = 0; df < 4; ++df) o[df][r] *= al;
      pv0[r] = p0; pv1[r] = p1;
    }
    // P -> LDS (per-wave region) to convert D-layout -> A-layout
    u16* Pw = PsF + wid * 16 * 32;
#pragma unroll
    for (int r = 0; r < 4; ++r){
      Pw[(fg * 4 + r) * 32 + fr]      = f2bf(pv0[r]);
      Pw[(fg * 4 + r) * 32 + 16 + fr] = f2bf(pv1[r]);
    }
    short8 pa = *(const short8*)(Pw + fr * 32 + fg * 8);
#pragma unroll
    for (int df = 0; df < 4; ++df){
      short8 bv = *(const short8*)(VsF + (fg * 64 + df * 16 + fr) * 8);
      o[df] = __builtin_amdgcn_mfma_f32_16x16x32_bf16(pa, bv, o[df], 0, 0, 0);
    }
  }
  // epilogue: y[t][h*64+d]
  for (int r = 0; r < 4; ++r){
    const int trow = qrow0 + fg * 4 + r;
    const float inv = 1.f / lrow[r];
    for (int df = 0; df < 4; ++df)
      yb[(size_t)trow * 2048 + h * 64 + df * 16 + fr] = f2bf(o[df][r] * inv);
  }
}

extern "C" void kernel_launch(void* const* d_in, const int* in_sizes, int n_in,
                              void* d_out, int out_size, void* d_ws, size_t ws_size,
                              hipStream_t stream){
  (void)in_sizes; (void)n_in; (void)out_size; (void)ws_size;
  const float* x     = (const float*)d_in[0];
  const float* Wqkv  = (const float*)d_in[1];
  const float* Wproj = (const float*)d_in[2];
  const float* qg    = (const float*)d_in[3];
  const float* at    = (const float*)d_in[4];
  float* out = (float*)d_out;

  // workspace layout (75.5 MB total)
  u16*   xb     = (u16*)d_ws;                    // 2048*2048 bf16
  u16*   wqkvb  = xb + 4194304;                  // 3072*2048 bf16
  u16*   wprojb = wqkvb + 6291456;               // 2048*2048 bf16
  float* qkv    = (float*)(wprojb + 4194304);    // 2048*3072 fp32
  u16*   qbuf   = (u16*)(qkv + 6291456);         // 32*2048*64 bf16
  u16*   kbuf   = qbuf + 4194304;                // 8*2048*64 bf16
  u16*   vbuf   = kbuf + 1048576;                // 8*2048*64 bf16
  u16*   ybuf   = vbuf + 1048576;                // 2048*2048 bf16

  cvt_bf16<<<4096, 256, 0, stream>>>((const float4*)x,     xb,     1048576);
  cvt_bf16<<<6144, 256, 0, stream>>>((const float4*)Wqkv,  wqkvb,  1572864);
  cvt_bf16<<<4096, 256, 0, stream>>>((const float4*)Wproj, wprojb, 1048576);
  gemm_bt<<<dim3(24, 16), 256, 0, stream>>>(xb, wqkvb, qkv, 2048, 3072, 2048);
  rope_pack<<<2048, 256, 0, stream>>>(qkv, qg, at, qbuf, kbuf, vbuf);
  attn_fwd<<<dim3(32, 32), 256, 0, stream>>>(qbuf, kbuf, vbuf, ybuf);
  gemm_bt<<<dim3(16, 16), 256, 0, stream>>>(ybuf, wprojb, out, 2048, 2048, 2048);
}

// Round 3
// 241.056 us; speedup vs baseline: 1.5198x; 1.5198x over previous
//
#include <hip/hip_runtime.h>
#include <hip/hip_bf16.h>

typedef unsigned short u16;
typedef __attribute__((ext_vector_type(8))) short short8;
typedef __attribute__((ext_vector_type(4))) float f32x4;
typedef __attribute__((ext_vector_type(4))) unsigned short u16x4;

#define DEVI static __device__ __forceinline__

DEVI u16 f2bf(float f){
  union { float f; unsigned u; } c; c.f = f;
  unsigned r = (c.u + 0x7fffu + ((c.u >> 16) & 1u)) >> 16;
  return (u16)r;
}

DEVI void async16(const void* g, void* l){
  __builtin_amdgcn_global_load_lds(
    (const __attribute__((address_space(1))) unsigned int*)g,
    (__attribute__((address_space(3))) unsigned int*)l, 16, 0, 0);
}

// ---------------- fp32 -> bf16 conversion ----------------
__global__ __launch_bounds__(256) void cvt_bf16(const float4* __restrict__ src,
                                                u16* __restrict__ dst, int n4){
  int i = blockIdx.x * 256 + threadIdx.x;
  if (i >= n4) return;
  float4 v = src[i];
  u16x4 o;
  o.x = f2bf(v.x); o.y = f2bf(v.y); o.z = f2bf(v.z); o.w = f2bf(v.w);
  *(u16x4*)(dst + (size_t)i * 4) = o;
}

// ---------------- GEMM: C[M][N] = A[M][K] * B[N][K]^T ----------------
__global__ __launch_bounds__(256) void gemm_bt(const u16* __restrict__ A,
                                               const u16* __restrict__ B,
                                               float* __restrict__ C,
                                               int M, int N, int K){
  __shared__ __align__(16) u16 AsF[4 * 128 * 8];
  __shared__ __align__(16) u16 BsF[4 * 128 * 8];
  const int tid  = threadIdx.x;
  const int lane = tid & 63, wid = tid >> 6;
  const int wr = wid >> 1, wc = wid & 1;
  const int fr = lane & 15, fg = lane >> 4;
  const int mBase = blockIdx.y * 128, nBase = blockIdx.x * 128;

  f32x4 acc[4][4];
  for (int m = 0; m < 4; ++m)
    for (int n = 0; n < 4; ++n)
      for (int e = 0; e < 4; ++e) acc[m][n][e] = 0.f;

  const int ch0 = tid, ch1 = tid + 256;
  const int r0 = ch0 & 127, g0 = ch0 >> 7;
  const int r1 = ch1 & 127, g1 = ch1 >> 7;
  const u16* Ab = A + (size_t)mBase * K;
  const u16* Bb = B + (size_t)nBase * K;

  const int nk = K >> 5;
  for (int kt = 0; kt < nk; ++kt){
    const int kOff = kt * 32;
    async16(Ab + (size_t)r0 * K + kOff + g0 * 8, AsF + ch0 * 8);
    async16(Ab + (size_t)r1 * K + kOff + g1 * 8, AsF + ch1 * 8);
    async16(Bb + (size_t)r0 * K + kOff + g0 * 8, BsF + ch0 * 8);
    async16(Bb + (size_t)r1 * K + kOff + g1 * 8, BsF + ch1 * 8);
    __syncthreads();
    short8 a[4], b[4];
#pragma unroll
    for (int m = 0; m < 4; ++m)
      a[m] = *(const short8*)(AsF + (fg * 128 + wr * 64 + m * 16 + fr) * 8);
#pragma unroll
    for (int n = 0; n < 4; ++n)
      b[n] = *(const short8*)(BsF + (fg * 128 + wc * 64 + n * 16 + fr) * 8);
#pragma unroll
    for (int m = 0; m < 4; ++m)
#pragma unroll
      for (int n = 0; n < 4; ++n)
        acc[m][n] = __builtin_amdgcn_mfma_f32_16x16x32_bf16(a[m], b[n], acc[m][n], 0, 0, 0);
    __syncthreads();
  }
  for (int m = 0; m < 4; ++m){
    const int row = mBase + wr * 64 + m * 16 + fg * 4;
    for (int n = 0; n < 4; ++n){
      const int col = nBase + wc * 64 + n * 16 + fr;
      for (int e = 0; e < 4; ++e)
        C[(size_t)(row + e) * N + col] = acc[m][n][e];
    }
  }
}

// ---------------- RoPE + gain/scale + pack to bf16 head-major ----------------
__global__ __launch_bounds__(256) void rope_pack(const float* __restrict__ qkv,
                                                 const float* __restrict__ q_gain,
                                                 const float* __restrict__ attn_temp,
                                                 u16* __restrict__ qb,
                                                 u16* __restrict__ kb,
                                                 u16* __restrict__ vb){
  const int t = blockIdx.x;
  const float* row = qkv + (size_t)t * 3072;
  const int tid = threadIdx.x;
  const float ft = (float)t;
  for (int p = tid; p < 1024; p += 256){
    const int h = p >> 5, d = p & 31;
    const float x1 = row[h * 64 + d], x2 = row[h * 64 + d + 32];
    const float ang = ft * ((float)d * 0.03125f);
    const float s = sinf(ang), c = cosf(ang);
    const float gsc = q_gain[h] * attn_temp[h] * 0.125f;
    const size_t o = ((size_t)h * 2048 + t) * 64 + d;
    qb[o]      = f2bf((x1 * c - x2 * s) * gsc);
    qb[o + 32] = f2bf((x1 * s + x2 * c) * gsc);
  }
  {
    const int h = tid >> 5, d = tid & 31;
    const float x1 = row[2048 + h * 64 + d], x2 = row[2048 + h * 64 + d + 32];
    const float ang = ft * ((float)d * 0.03125f);
    const float s = sinf(ang), c = cosf(ang);
    const size_t o = ((size_t)h * 2048 + t) * 64 + d;
    kb[o]      = f2bf(x1 * c - x2 * s);
    kb[o + 32] = f2bf(x1 * s + x2 * c);
  }
  for (int p = tid; p < 512; p += 256){
    const int h = p >> 6, d = p & 63;
    vb[((size_t)h * 2048 + t) * 64 + d] = f2bf(row[2560 + p]);
  }
}

// ---------------- V transpose: vb[h][t][64] -> vT[h][d][2048] ----------------
__global__ __launch_bounds__(256) void transpose_v(const u16* __restrict__ vb,
                                                   u16* __restrict__ vT){
  const int h = blockIdx.y;
  const int t0 = blockIdx.x * 64;
  __shared__ __align__(16) u16 tile[64 * 72];
  const int tid = threadIdx.x;
#pragma unroll
  for (int cc = 0; cc < 2; ++cc){
    const int c = tid + cc * 256;
    const int row = c >> 3, c8 = c & 7;
    short8 v = *(const short8*)(vb + ((size_t)h * 2048 + t0 + row) * 64 + c8 * 8);
    *(short8*)(tile + row * 72 + c8 * 8) = v;
  }
  __syncthreads();
#pragma unroll
  for (int cc = 0; cc < 2; ++cc){
    const int c = tid + cc * 256;
    const int d = c & 63, t8 = c >> 6;
    short8 v;
#pragma unroll
    for (int j = 0; j < 8; ++j) v[j] = tile[(t8 * 8 + j) * 72 + d];
    *(short8*)(vT + ((size_t)h * 64 + d) * 2048 + t0 + t8 * 8) = v;
  }
}

// ---------------- causal flash attention v2 ----------------
// qb[32][2048][64], kb[8][2048][64], vT[8][64][2048] -> yb[2048][2048]
// 4 waves x 16 q-rows = 64 q/block; KVBLK=64; paired q-tiles (qt, 31-qt);
// K/V staged chunk-transposed linear via global_load_lds; double-buffered.
__global__ __launch_bounds__(256) void attn_fwd(const u16* __restrict__ qb,
                                                const u16* __restrict__ kb,
                                                const u16* __restrict__ vT,
                                                u16* __restrict__ yb){
  const int bx = blockIdx.x, h = blockIdx.y;
  const int hk = h >> 2;
  const int tid = threadIdx.x;
  const int lane = tid & 63, wid = tid >> 6;
  const int fr = lane & 15, fg = lane >> 4;

  __shared__ __align__(16) u16 Ks[2][4096];   // chunk c=g*64+row : K[row][g*8..+7]
  __shared__ __align__(16) u16 Vs[2][4096];   // chunk c=kc*64+d  : V^T[d][kc*8..+7]
  __shared__ __align__(16) u16 Ps[4][16 * 72];

  const u16* kbh = kb + (size_t)hk * 2048 * 64;
  const u16* vTh = vT + (size_t)hk * 64 * 2048;

  const int c0 = tid, c1 = tid + 256;
  const int kr0 = c0 & 63, kg0 = c0 >> 6;
  const int kr1 = c1 & 63, kg1 = c1 >> 6;

#pragma unroll 1
  for (int seg = 0; seg < 2; ++seg){
    const int qt = seg ? (31 - bx) : bx;
    const int nt = qt + 1;
    const int qrow0 = qt * 64 + wid * 16;

    short8 qf[2];
    {
      const u16* qp = qb + ((size_t)h * 2048 + qrow0 + fr) * 64 + fg * 8;
      qf[0] = *(const short8*)(qp);
      qf[1] = *(const short8*)(qp + 32);
    }

    float mrow[4], lrow[4];
    f32x4 o[4];
    for (int r = 0; r < 4; ++r){ mrow[r] = -1e30f; lrow[r] = 0.f; }
    for (int df = 0; df < 4; ++df)
      for (int e = 0; e < 4; ++e) o[df][e] = 0.f;

    // prologue: stage tile 0 into buffer 0
    {
      async16(kbh + (size_t)kr0 * 64 + kg0 * 8, &Ks[0][c0 * 8]);
      async16(kbh + (size_t)kr1 * 64 + kg1 * 8, &Ks[0][c1 * 8]);
      async16(vTh + (size_t)kr0 * 2048 + kg0 * 8, &Vs[0][c0 * 8]);
      async16(vTh + (size_t)kr1 * 2048 + kg1 * 8, &Vs[0][c1 * 8]);
    }

#pragma unroll 1
    for (int kt = 0; kt < nt; ++kt){
      const int cur = kt & 1;
      __syncthreads();   // drains vmcnt (stage kt) + syncs buffer reuse
      if (kt + 1 < nt){
        const int nxt = cur ^ 1;
        const size_t kO = (size_t)(kt + 1) * 64;
        async16(kbh + (kO + kr0) * 64 + kg0 * 8, &Ks[nxt][c0 * 8]);
        async16(kbh + (kO + kr1) * 64 + kg1 * 8, &Ks[nxt][c1 * 8]);
        async16(vTh + (size_t)kr0 * 2048 + kO + kg0 * 8, &Vs[nxt][c0 * 8]);
        async16(vTh + (size_t)kr1 * 2048 + kO + kg1 * 8, &Vs[nxt][c1 * 8]);
      }
      const u16* Kb = Ks[cur];
      const u16* Vb = Vs[cur];

      // S = Q K^T : 4 col-frags x (K-dim 64 = 2 mfma)
      f32x4 s[4];
      __builtin_amdgcn_s_setprio(1);
#pragma unroll
      for (int cf = 0; cf < 4; ++cf){
        for (int e = 0; e < 4; ++e) s[cf][e] = 0.f;
#pragma unroll
        for (int kc = 0; kc < 2; ++kc){
          short8 kf = *(const short8*)(Kb + ((kc * 4 + fg) * 64 + cf * 16 + fr) * 8);
          s[cf] = __builtin_amdgcn_mfma_f32_16x16x32_bf16(qf[kc], kf, s[cf], 0, 0, 0);
        }
      }
      __builtin_amdgcn_s_setprio(0);

      // causal mask
      if (kt * 64 + 63 > qrow0){
#pragma unroll
        for (int cf = 0; cf < 4; ++cf){
          const int kcol = kt * 64 + cf * 16 + fr;
#pragma unroll
          for (int r = 0; r < 4; ++r)
            if (kcol > qrow0 + fg * 4 + r) s[cf][r] = -1e30f;
        }
      }

      // online softmax (rows in 16-lane groups)
      float pv[4][4];
#pragma unroll
      for (int r = 0; r < 4; ++r){
        float mt = fmaxf(fmaxf(s[0][r], s[1][r]), fmaxf(s[2][r], s[3][r]));
        for (int msk = 1; msk < 16; msk <<= 1) mt = fmaxf(mt, __shfl_xor(mt, msk, 16));
        const float mn = fmaxf(mrow[r], mt);
        const float al = __expf(mrow[r] - mn);
        float rs = 0.f;
#pragma unroll
        for (int cf = 0; cf < 4; ++cf){
          const float p = __expf(s[cf][r] - mn);
          pv[cf][r] = p; rs += p;
        }
        for (int msk = 1; msk < 16; msk <<= 1) rs += __shfl_xor(rs, msk, 16);
        mrow[r] = mn;
        lrow[r] = lrow[r] * al + rs;
#pragma unroll
        for (int df = 0; df < 4; ++df) o[df][r] *= al;
      }

      // P -> per-wave LDS (stride 72), read back as A-frags
      u16* Pw = &Ps[wid][0];
#pragma unroll
      for (int r = 0; r < 4; ++r)
#pragma unroll
        for (int cf = 0; cf < 4; ++cf)
          Pw[(fg * 4 + r) * 72 + cf * 16 + fr] = f2bf(pv[cf][r]);
      short8 pa0 = *(const short8*)(Pw + fr * 72 + fg * 8);
      short8 pa1 = *(const short8*)(Pw + fr * 72 + 32 + fg * 8);

      __builtin_amdgcn_s_setprio(1);
#pragma unroll
      for (int df = 0; df < 4; ++df){
        short8 v0 = *(const short8*)(Vb + ((0 * 4 + fg) * 64 + df * 16 + fr) * 8);
        short8 v1 = *(const short8*)(Vb + ((1 * 4 + fg) * 64 + df * 16 + fr) * 8);
        o[df] = __builtin_amdgcn_mfma_f32_16x16x32_bf16(pa0, v0, o[df], 0, 0, 0);
        o[df] = __builtin_amdgcn_mfma_f32_16x16x32_bf16(pa1, v1, o[df], 0, 0, 0);
      }
      __builtin_amdgcn_s_setprio(0);
    }
    __syncthreads();   // protect LDS before next segment's prologue stage

    // epilogue
#pragma unroll
    for (int r = 0; r < 4; ++r){
      const int trow = qrow0 + fg * 4 + r;
      const float inv = 1.f / lrow[r];
#pragma unroll
      for (int df = 0; df < 4; ++df)
        yb[(size_t)trow * 2048 + h * 64 + df * 16 + fr] = f2bf(o[df][r] * inv);
    }
  }
}

extern "C" void kernel_launch(void* const* d_in, const int* in_sizes, int n_in,
                              void* d_out, int out_size, void* d_ws, size_t ws_size,
                              hipStream_t stream){
  (void)in_sizes; (void)n_in; (void)out_size; (void)ws_size;
  const float* x     = (const float*)d_in[0];
  const float* Wqkv  = (const float*)d_in[1];
  const float* Wproj = (const float*)d_in[2];
  const float* qg    = (const float*)d_in[3];
  const float* at    = (const float*)d_in[4];
  float* out = (float*)d_out;

  u16*   xb     = (u16*)d_ws;                    // 2048*2048 bf16
  u16*   wqkvb  = xb + 4194304;                  // 3072*2048 bf16
  u16*   wprojb = wqkvb + 6291456;               // 2048*2048 bf16
  float* qkv    = (float*)(wprojb + 4194304);    // 2048*3072 fp32
  u16*   qbuf   = (u16*)(qkv + 6291456);         // 32*2048*64 bf16
  u16*   kbuf   = qbuf + 4194304;                // 8*2048*64 bf16
  u16*   vbuf   = kbuf + 1048576;                // 8*2048*64 bf16
  u16*   ybuf   = vbuf + 1048576;                // 2048*2048 bf16
  u16*   vTb    = (u16*)qkv;                     // alias: qkv dead after rope_pack

  cvt_bf16<<<4096, 256, 0, stream>>>((const float4*)x,     xb,     1048576);
  cvt_bf16<<<6144, 256, 0, stream>>>((const float4*)Wqkv,  wqkvb,  1572864);
  cvt_bf16<<<4096, 256, 0, stream>>>((const float4*)Wproj, wprojb, 1048576);
  gemm_bt<<<dim3(24, 16), 256, 0, stream>>>(xb, wqkvb, qkv, 2048, 3072, 2048);
  rope_pack<<<2048, 256, 0, stream>>>(qkv, qg, at, qbuf, kbuf, vbuf);
  transpose_v<<<dim3(32, 8), 256, 0, stream>>>(vbuf, vTb);
  attn_fwd<<<dim3(16, 32), 256, 0, stream>>>(qbuf, kbuf, vTb, ybuf);
  gemm_bt<<<dim3(16, 16), 256, 0, stream>>>(ybuf, wprojb, out, 2048, 2048, 2048);
}

// Round 4
// 203.010 us; speedup vs baseline: 1.8046x; 1.1874x over previous
//
#include <hip/hip_runtime.h>
#include <hip/hip_bf16.h>
#include <math.h>

typedef unsigned short u16;
typedef __attribute__((ext_vector_type(8))) short short8;
typedef __attribute__((ext_vector_type(4))) float f32x4;
typedef __attribute__((ext_vector_type(4))) unsigned short u16x4;
typedef __attribute__((ext_vector_type(4))) unsigned int u32x4;

#define DEVI static __device__ __forceinline__

DEVI u16 f2bf(float f){
  union { float f; unsigned u; } c; c.f = f;
  unsigned r = (c.u + 0x7fffu + ((c.u >> 16) & 1u)) >> 16;
  return (u16)r;
}

DEVI unsigned cvtpk(float lo, float hi){
  unsigned r;
  asm("v_cvt_pk_bf16_f32 %0, %1, %2" : "=v"(r) : "v"(lo), "v"(hi));
  return r;
}

DEVI void async16(const void* g, void* l){
  __builtin_amdgcn_global_load_lds(
    (const __attribute__((address_space(1))) unsigned int*)g,
    (__attribute__((address_space(3))) unsigned int*)l, 16, 0, 0);
}

// ---------------- fused fp32 -> bf16 conversion (x, Wqkv, Wproj) ----------------
__global__ __launch_bounds__(256) void cvt3(const float4* __restrict__ x,
                                            const float4* __restrict__ wq,
                                            const float4* __restrict__ wp,
                                            u16* __restrict__ xb,
                                            u16* __restrict__ wqb,
                                            u16* __restrict__ wpb){
  int i = blockIdx.x * 256 + threadIdx.x;
  const float4* s; u16* d; int off;
  if (i < 1048576)      { s = x;  d = xb;  off = i; }
  else if (i < 2621440) { s = wq; d = wqb; off = i - 1048576; }
  else                  { s = wp; d = wpb; off = i - 2621440; }
  float4 v = s[off];
  u16x4 o;
  o.x = f2bf(v.x); o.y = f2bf(v.y); o.z = f2bf(v.z); o.w = f2bf(v.w);
  *(u16x4*)(d + (size_t)off * 4) = o;
}

// ---------------- qkv GEMM fused with RoPE/gain/pack + V-transpose ----------------
// xb[2048][2048] * wqkvb[3072][2048]^T ; epilogue writes
// qb[32][2048][64], kb[8][2048][64] (RoPE'd), vT[8][64][2048] (transposed), all bf16.
__global__ __launch_bounds__(256) void gemm_qkv(const u16* __restrict__ A,
                                                const u16* __restrict__ B,
                                                const float* __restrict__ qg,
                                                const float* __restrict__ at_,
                                                u16* __restrict__ qb,
                                                u16* __restrict__ kb,
                                                u16* __restrict__ vT){
  const int K = 2048;
  __shared__ __align__(16) u16 As[2][4096];
  __shared__ __align__(16) u16 Bs[2][4096];
  const int tid  = threadIdx.x;
  const int lane = tid & 63, wid = tid >> 6;
  const int wr = wid >> 1, wc = wid & 1;
  const int fr = lane & 15, fg = lane >> 4;
  const int mBase = blockIdx.y * 128, nBase = blockIdx.x * 128;

  f32x4 acc[4][4];
  for (int m = 0; m < 4; ++m)
    for (int n = 0; n < 4; ++n)
      for (int e = 0; e < 4; ++e) acc[m][n][e] = 0.f;

  const int ch0 = tid, ch1 = tid + 256;
  const int r0 = ch0 & 127, g0 = ch0 >> 7;
  const int r1 = ch1 & 127, g1 = ch1 >> 7;
  const u16* Ab = A + (size_t)mBase * K;
  const u16* Bb = B + (size_t)nBase * K;

  // prologue
  async16(Ab + (size_t)r0 * K + g0 * 8, As[0] + ch0 * 8);
  async16(Ab + (size_t)r1 * K + g1 * 8, As[0] + ch1 * 8);
  async16(Bb + (size_t)r0 * K + g0 * 8, Bs[0] + ch0 * 8);
  async16(Bb + (size_t)r1 * K + g1 * 8, Bs[0] + ch1 * 8);

#pragma unroll 1
  for (int kt = 0; kt < 64; ++kt){
    const int cur = kt & 1;
    __syncthreads();
    if (kt + 1 < 64){
      const int nxt = cur ^ 1, kO = (kt + 1) * 32;
      async16(Ab + (size_t)r0 * K + kO + g0 * 8, As[nxt] + ch0 * 8);
      async16(Ab + (size_t)r1 * K + kO + g1 * 8, As[nxt] + ch1 * 8);
      async16(Bb + (size_t)r0 * K + kO + g0 * 8, Bs[nxt] + ch0 * 8);
      async16(Bb + (size_t)r1 * K + kO + g1 * 8, Bs[nxt] + ch1 * 8);
    }
    short8 a[4], b[4];
#pragma unroll
    for (int m = 0; m < 4; ++m)
      a[m] = *(const short8*)(As[cur] + (fg * 128 + wr * 64 + m * 16 + fr) * 8);
#pragma unroll
    for (int n = 0; n < 4; ++n)
      b[n] = *(const short8*)(Bs[cur] + (fg * 128 + wc * 64 + n * 16 + fr) * 8);
    __builtin_amdgcn_s_setprio(1);
#pragma unroll
    for (int m = 0; m < 4; ++m)
#pragma unroll
      for (int n = 0; n < 4; ++n)
        acc[m][n] = __builtin_amdgcn_mfma_f32_16x16x32_bf16(a[m], b[n], acc[m][n], 0, 0, 0);
    __builtin_amdgcn_s_setprio(0);
  }

  // fused epilogue. col64-block: 0..31 = q heads, 32..39 = k heads, 40..47 = v heads
  const int nb64 = blockIdx.x * 2 + wc;
  if (nb64 < 40){
    const bool isq = nb64 < 32;
    const int h = isq ? nb64 : (nb64 - 32);
    const float gsc = isq ? (qg[h] * at_[h] * 0.125f) : 1.0f;
    u16* dst = isq ? qb : kb;
#pragma unroll
    for (int m = 0; m < 4; ++m)
#pragma unroll
      for (int e = 0; e < 4; ++e){
        const int t = mBase + wr * 64 + m * 16 + fg * 4 + e;
        const float ft = (float)t;
#pragma unroll
        for (int np = 0; np < 2; ++np){
          const int d = np * 16 + fr;
          const float ang = ft * ((float)d * 0.03125f);
          float sn, cs; sincosf(ang, &sn, &cs);
          const float x1 = acc[m][np][e], x2 = acc[m][np + 2][e];
          u16* base = dst + ((size_t)h * 2048 + t) * 64 + d;
          base[0]  = f2bf((x1 * cs - x2 * sn) * gsc);
          base[32] = f2bf((x1 * sn + x2 * cs) * gsc);
        }
      }
  } else {
    const int h = nb64 - 40;
#pragma unroll
    for (int m = 0; m < 4; ++m){
      const int t0 = mBase + wr * 64 + m * 16 + fg * 4;
#pragma unroll
      for (int n = 0; n < 4; ++n){
        const int d = n * 16 + fr;
        u16x4 pk;
#pragma unroll
        for (int e = 0; e < 4; ++e) pk[e] = f2bf(acc[m][n][e]);
        *(u16x4*)(vT + ((size_t)h * 64 + d) * 2048 + t0) = pk;
      }
    }
  }
}

// ---------------- causal flash attention v3 (swapped QK^T, lane-local softmax) ----
// qb[32][2048][64], kb[8][2048][64], vT[8][64][2048] -> yb[2048][2048]
// S^T = mfma(K,Q): lane owns q=fr, 16 S-values. K rows pi-permuted at staging so the
// owned S^T registers ARE the PV B-fragment after cvt_pk (zero shuffles, zero P-LDS).
__global__ __launch_bounds__(256) void attn_fwd(const u16* __restrict__ qb,
                                                const u16* __restrict__ kb,
                                                const u16* __restrict__ vT,
                                                u16* __restrict__ yb){
  const int bx = blockIdx.x, h = blockIdx.y;
  const int hk = h >> 2;
  const int tid = threadIdx.x;
  const int lane = tid & 63, wid = tid >> 6;
  const int fr = lane & 15, fg = lane >> 4;

  __shared__ __align__(16) u16 Ks[2][4096];   // chunk c=g*64+rho : K[pi(rho)][g*8..+7]
  __shared__ __align__(16) u16 Vs[2][4096];   // chunk c=g*64+d   : V^T[d][g*8..+7]

  const u16* kbh = kb + (size_t)hk * 2048 * 64;
  const u16* vTh = vT + (size_t)hk * 64 * 2048;

  const int rho = tid & 63, gk = tid >> 6;
  // pi: [kc cc fg1 fg0 r1 r0] -> kc*32 + fg*8 + cc*4 + r
  const int prow = ((rho >> 5) << 5) | (((rho >> 2) & 3) << 3) | (((rho >> 4) & 1) << 2) | (rho & 3);

#pragma unroll 1
  for (int seg = 0; seg < 2; ++seg){
    const int qt = seg ? (31 - bx) : bx;
    const int nt = qt + 1;
    const int qrow0 = qt * 64 + wid * 16;
    const int q = qrow0 + fr;          // this lane's q-row

    short8 qf[2];
    {
      const u16* qp = qb + ((size_t)h * 2048 + q) * 64 + fg * 8;
      qf[0] = *(const short8*)(qp);
      qf[1] = *(const short8*)(qp + 32);
    }

    float mrow = -1e30f, lrow = 0.f;
    f32x4 o[4];
    for (int df = 0; df < 4; ++df)
      for (int e = 0; e < 4; ++e) o[df][e] = 0.f;

    // prologue: stage tile 0 into buffer 0
    async16(kbh + (size_t)prow * 64 + gk * 8,       Ks[0] + (size_t)tid * 8);
    async16(kbh + (size_t)prow * 64 + (gk + 4) * 8, Ks[0] + (size_t)(tid + 256) * 8);
    async16(vTh + (size_t)rho * 2048 + gk * 8,       Vs[0] + (size_t)tid * 8);
    async16(vTh + (size_t)rho * 2048 + (gk + 4) * 8, Vs[0] + (size_t)(tid + 256) * 8);

#pragma unroll 1
    for (int kt = 0; kt < nt; ++kt){
      const int cur = kt & 1;
      __syncthreads();   // drains stage(kt), syncs buffer reuse
      if (kt + 1 < nt){
        const int nxt = cur ^ 1;
        const size_t kO = (size_t)(kt + 1) * 64;
        async16(kbh + (kO + prow) * 64 + gk * 8,       Ks[nxt] + (size_t)tid * 8);
        async16(kbh + (kO + prow) * 64 + (gk + 4) * 8, Ks[nxt] + (size_t)(tid + 256) * 8);
        async16(vTh + (size_t)rho * 2048 + kO + gk * 8,       Vs[nxt] + (size_t)tid * 8);
        async16(vTh + (size_t)rho * 2048 + kO + (gk + 4) * 8, Vs[nxt] + (size_t)(tid + 256) * 8);
      }
      const u16* Kb = Ks[cur];
      const u16* Vb = Vs[cur];

      // S^T = K_tile . Q^T : s[cf][r] = S[q][kt*64 + (cf>>1)*32 + fg*8 + (cf&1)*4 + r]
      f32x4 s[4];
      __builtin_amdgcn_s_setprio(1);
#pragma unroll
      for (int cf = 0; cf < 4; ++cf){
        for (int e = 0; e < 4; ++e) s[cf][e] = 0.f;
#pragma unroll
        for (int kc = 0; kc < 2; ++kc){
          short8 kf = *(const short8*)(Kb + ((kc * 4 + fg) * 64 + cf * 16 + fr) * 8);
          s[cf] = __builtin_amdgcn_mfma_f32_16x16x32_bf16(kf, qf[kc], s[cf], 0, 0, 0);
        }
      }
      __builtin_amdgcn_s_setprio(0);

      // causal mask
      if (kt * 64 + 63 > qrow0){
#pragma unroll
        for (int cf = 0; cf < 4; ++cf){
          const int kb0 = kt * 64 + (cf >> 1) * 32 + (cf & 1) * 4 + fg * 8;
#pragma unroll
          for (int r = 0; r < 4; ++r)
            if (kb0 + r > q) s[cf][r] = -1e30f;
        }
      }

      // lane-local softmax with defer-max
      float m0 = fmaxf(fmaxf(s[0][0], s[0][1]), fmaxf(s[0][2], s[0][3]));
      float m1 = fmaxf(fmaxf(s[1][0], s[1][1]), fmaxf(s[1][2], s[1][3]));
      float m2 = fmaxf(fmaxf(s[2][0], s[2][1]), fmaxf(s[2][2], s[2][3]));
      float m3 = fmaxf(fmaxf(s[3][0], s[3][1]), fmaxf(s[3][2], s[3][3]));
      float mt = fmaxf(fmaxf(m0, m1), fmaxf(m2, m3));
      mt = fmaxf(mt, __shfl_xor(mt, 16));
      mt = fmaxf(mt, __shfl_xor(mt, 32));
      if (!__all(mt <= mrow + 8.f)){
        const float mn = fmaxf(mrow, mt);
        const float al = __expf(mrow - mn);
        lrow *= al;
#pragma unroll
        for (int df = 0; df < 4; ++df)
#pragma unroll
          for (int e = 0; e < 4; ++e) o[df][e] *= al;
        mrow = mn;
      }
      float rs = 0.f;
#pragma unroll
      for (int cf = 0; cf < 4; ++cf){
#pragma unroll
        for (int r = 0; r < 4; ++r){
          s[cf][r] = __expf(s[cf][r] - mrow);
          rs += s[cf][r];
        }
      }
      rs += __shfl_xor(rs, 16);
      rs += __shfl_xor(rs, 32);
      lrow += rs;

      // pack P -> PV B-fragments fully in-register (pi makes owned regs = needed k-slice)
      union { u32x4 u; short8 s8; } pb0, pb1;
      pb0.u[0] = cvtpk(s[0][0], s[0][1]); pb0.u[1] = cvtpk(s[0][2], s[0][3]);
      pb0.u[2] = cvtpk(s[1][0], s[1][1]); pb0.u[3] = cvtpk(s[1][2], s[1][3]);
      pb1.u[0] = cvtpk(s[2][0], s[2][1]); pb1.u[1] = cvtpk(s[2][2], s[2][3]);
      pb1.u[2] = cvtpk(s[3][0], s[3][1]); pb1.u[3] = cvtpk(s[3][2], s[3][3]);

      // O^T += V^T . P^T
      __builtin_amdgcn_s_setprio(1);
#pragma unroll
      for (int df = 0; df < 4; ++df){
        short8 v0 = *(const short8*)(Vb + ((0 * 4 + fg) * 64 + df * 16 + fr) * 8);
        short8 v1 = *(const short8*)(Vb + ((1 * 4 + fg) * 64 + df * 16 + fr) * 8);
        o[df] = __builtin_amdgcn_mfma_f32_16x16x32_bf16(v0, pb0.s8, o[df], 0, 0, 0);
        o[df] = __builtin_amdgcn_mfma_f32_16x16x32_bf16(v1, pb1.s8, o[df], 0, 0, 0);
      }
      __builtin_amdgcn_s_setprio(0);
    }
    __syncthreads();   // protect LDS before next segment's prologue stage

    // epilogue: O^T[d][q] -> y[q][h*64+d]; d = df*16 + fg*4 + e
    const float inv = 1.f / lrow;
#pragma unroll
    for (int df = 0; df < 4; ++df){
      u16x4 pk;
#pragma unroll
      for (int e = 0; e < 4; ++e) pk[e] = f2bf(o[df][e] * inv);
      *(u16x4*)(yb + (size_t)q * 2048 + h * 64 + df * 16 + fg * 4) = pk;
    }
  }
}

// ---------------- proj GEMM: C[M][N] = A[M][K] * B[N][K]^T (fp32 out, dbuf) -------
__global__ __launch_bounds__(256) void gemm_bt(const u16* __restrict__ A,
                                               const u16* __restrict__ B,
                                               float* __restrict__ C,
                                               int M, int N, int K){
  __shared__ __align__(16) u16 As[2][4096];
  __shared__ __align__(16) u16 Bs[2][4096];
  const int tid  = threadIdx.x;
  const int lane = tid & 63, wid = tid >> 6;
  const int wr = wid >> 1, wc = wid & 1;
  const int fr = lane & 15, fg = lane >> 4;
  const int mBase = blockIdx.y * 128, nBase = blockIdx.x * 128;

  f32x4 acc[4][4];
  for (int m = 0; m < 4; ++m)
    for (int n = 0; n < 4; ++n)
      for (int e = 0; e < 4; ++e) acc[m][n][e] = 0.f;

  const int ch0 = tid, ch1 = tid + 256;
  const int r0 = ch0 & 127, g0 = ch0 >> 7;
  const int r1 = ch1 & 127, g1 = ch1 >> 7;
  const u16* Ab = A + (size_t)mBase * K;
  const u16* Bb = B + (size_t)nBase * K;

  async16(Ab + (size_t)r0 * K + g0 * 8, As[0] + ch0 * 8);
  async16(Ab + (size_t)r1 * K + g1 * 8, As[0] + ch1 * 8);
  async16(Bb + (size_t)r0 * K + g0 * 8, Bs[0] + ch0 * 8);
  async16(Bb + (size_t)r1 * K + g1 * 8, Bs[0] + ch1 * 8);

  const int nk = K >> 5;
#pragma unroll 1
  for (int kt = 0; kt < nk; ++kt){
    const int cur = kt & 1;
    __syncthreads();
    if (kt + 1 < nk){
      const int nxt = cur ^ 1, kO = (kt + 1) * 32;
      async16(Ab + (size_t)r0 * K + kO + g0 * 8, As[nxt] + ch0 * 8);
      async16(Ab + (size_t)r1 * K + kO + g1 * 8, As[nxt] + ch1 * 8);
      async16(Bb + (size_t)r0 * K + kO + g0 * 8, Bs[nxt] + ch0 * 8);
      async16(Bb + (size_t)r1 * K + kO + g1 * 8, Bs[nxt] + ch1 * 8);
    }
    short8 a[4], b[4];
#pragma unroll
    for (int m = 0; m < 4; ++m)
      a[m] = *(const short8*)(As[cur] + (fg * 128 + wr * 64 + m * 16 + fr) * 8);
#pragma unroll
    for (int n = 0; n < 4; ++n)
      b[n] = *(const short8*)(Bs[cur] + (fg * 128 + wc * 64 + n * 16 + fr) * 8);
    __builtin_amdgcn_s_setprio(1);
#pragma unroll
    for (int m = 0; m < 4; ++m)
#pragma unroll
      for (int n = 0; n < 4; ++n)
        acc[m][n] = __builtin_amdgcn_mfma_f32_16x16x32_bf16(a[m], b[n], acc[m][n], 0, 0, 0);
    __builtin_amdgcn_s_setprio(0);
  }
  for (int m = 0; m < 4; ++m){
    const int row = mBase + wr * 64 + m * 16 + fg * 4;
    for (int n = 0; n < 4; ++n){
      const int col = nBase + wc * 64 + n * 16 + fr;
      for (int e = 0; e < 4; ++e)
        C[(size_t)(row + e) * N + col] = acc[m][n][e];
    }
  }
}

extern "C" void kernel_launch(void* const* d_in, const int* in_sizes, int n_in,
                              void* d_out, int out_size, void* d_ws, size_t ws_size,
                              hipStream_t stream){
  (void)in_sizes; (void)n_in; (void)out_size; (void)ws_size;
  const float* x     = (const float*)d_in[0];
  const float* Wqkv  = (const float*)d_in[1];
  const float* Wproj = (const float*)d_in[2];
  const float* qg    = (const float*)d_in[3];
  const float* at    = (const float*)d_in[4];
  float* out = (float*)d_out;

  // workspace layout (u16 units, ~50MB total)
  u16* xb     = (u16*)d_ws;              // 2048*2048
  u16* wqkvb  = xb + 4194304;            // 3072*2048
  u16* wprojb = wqkvb + 6291456;         // 2048*2048
  u16* qbuf   = wprojb + 4194304;        // 32*2048*64
  u16* kbuf   = qbuf + 4194304;          // 8*2048*64
  u16* vTb    = kbuf + 1048576;          // 8*64*2048
  u16* ybuf   = vTb + 1048576;           // 2048*2048

  cvt3<<<14336, 256, 0, stream>>>((const float4*)x, (const float4*)Wqkv,
                                  (const float4*)Wproj, xb, wqkvb, wprojb);
  gemm_qkv<<<dim3(24, 16), 256, 0, stream>>>(xb, wqkvb, qg, at, qbuf, kbuf, vTb);
  attn_fwd<<<dim3(16, 32), 256, 0, stream>>>(qbuf, kbuf, vTb, ybuf);
  gemm_bt<<<dim3(16, 16), 256, 0, stream>>>(ybuf, wprojb, out, 2048, 2048, 2048);
}